// Round 1
// baseline (212.315 us; speedup 1.0000x reference)
//
#include <hip/hip_runtime.h>

#define LOG2E 1.4426950408889634f

// Problem constants
constexpr int Bb = 4, LQ = 512, LK = 512, QS = 512, H = 256, DV = 512;

// ---------------------------------------------------------------------------
// Kernel A: fused Q/K projection.  C[M,N] = (A[M,K] @ W[N,K]^T + bias[N])*scale
// M = B*L = 2048, K = 512, N = H = 256.  Tiles 64x64, BK=32, 256 thr, 4x4/thr.
// blockIdx.z selects Q (0) vs K (1).  scale = 2*log2(e) folds tanh's exp into
// exp2 later.
// ---------------------------------------------------------------------------
__global__ __launch_bounds__(256) void proj2_kernel(
    const float* __restrict__ Aq, const float* __restrict__ Ak,
    const float* __restrict__ Wq, const float* __restrict__ Wk,
    const float* __restrict__ Bq, const float* __restrict__ Bk,
    float* __restrict__ Cq, float* __restrict__ Ck, float scale)
{
    const int K = QS, N = H;
    const float* A    = blockIdx.z ? Ak : Aq;
    const float* W    = blockIdx.z ? Wk : Wq;
    const float* bias = blockIdx.z ? Bk : Bq;
    float*       C    = blockIdx.z ? Ck : Cq;

    __shared__ float As[32][64];
    __shared__ float Ws[32][64];
    const int bm = blockIdx.x * 64;
    const int bn = blockIdx.y * 64;
    const int tid = threadIdx.x;
    const int tx = tid & 15, ty = tid >> 4;
    float acc[4][4] = {};

    for (int k0 = 0; k0 < K; k0 += 32) {
#pragma unroll
        for (int it = 0; it < 2; ++it) {
            int f = tid + it * 256;      // 0..511
            int r = f >> 3;              // 0..63
            int c = (f & 7) * 4;         // 0..28
            float4 av = *(const float4*)(A + (size_t)(bm + r) * K + k0 + c);
            As[c + 0][r] = av.x; As[c + 1][r] = av.y;
            As[c + 2][r] = av.z; As[c + 3][r] = av.w;
            float4 wv4 = *(const float4*)(W + (size_t)(bn + r) * K + k0 + c);
            Ws[c + 0][r] = wv4.x; Ws[c + 1][r] = wv4.y;
            Ws[c + 2][r] = wv4.z; Ws[c + 3][r] = wv4.w;
        }
        __syncthreads();
#pragma unroll
        for (int k = 0; k < 32; ++k) {
            const float4 a4 = *(const float4*)&As[k][tx * 4];
            const float4 b4 = *(const float4*)&Ws[k][ty * 4];
            const float a[4] = {a4.x, a4.y, a4.z, a4.w};
            const float b[4] = {b4.x, b4.y, b4.z, b4.w};
#pragma unroll
            for (int i = 0; i < 4; ++i)
#pragma unroll
                for (int j = 0; j < 4; ++j)
                    acc[i][j] = fmaf(a[i], b[j], acc[i][j]);
        }
        __syncthreads();
    }
#pragma unroll
    for (int i = 0; i < 4; ++i) {
        int m = bm + tx * 4 + i;
#pragma unroll
        for (int j = 0; j < 4; ++j) {
            int n = bn + ty * 4 + j;
            C[(size_t)m * N + n] = (acc[i][j] + bias[n]) * scale;
        }
    }
}

// ---------------------------------------------------------------------------
// Kernel B: scores (log2 domain, bv dropped — softmax shift-invariant).
//   s'[b,q,k] = log2e * sum_h wv[h]*tanh(arg)  where arg = q_raw+k_raw and
//   Qp/Kp already hold 2*log2e*(proj+bias), so tanh = 1 - 2*rcp(exp2(x)+1).
//   s' = SW - sum_h Wv2[h]*rcp(exp2(Qp+Kp)+1),  Wv2 = 2*log2e*wv, SW = 0.5*ΣWv2
// Tiles 64(q) x 64(k), h-chunk 32, 256 thr, 4x4/thr. Grid (8,8,B).
// ---------------------------------------------------------------------------
__global__ __launch_bounds__(256) void score_kernel(
    const float* __restrict__ Qp,   // [B*LQ, H]
    const float* __restrict__ Kp,   // [B*LK, H]
    const float* __restrict__ wv,   // [H]
    float* __restrict__ Sc)         // [B*LQ, LK]
{
    __shared__ float Qs[32][64], Ks[32][64];
    __shared__ float Wv2[H];
    const int b  = blockIdx.z;
    const int qb = blockIdx.x * 64, kb = blockIdx.y * 64;
    const int tid = threadIdx.x;
    const int tx = tid & 15, ty = tid >> 4;

    Wv2[tid] = wv[tid] * (2.0f * LOG2E);   // blockDim == H == 256
    __syncthreads();

    float SW;
    {
        float s0 = 0.f, s1 = 0.f, s2 = 0.f, s3 = 0.f;
        for (int h = 0; h < H; h += 4) {
            s0 += Wv2[h + 0]; s1 += Wv2[h + 1];
            s2 += Wv2[h + 2]; s3 += Wv2[h + 3];
        }
        SW = 0.5f * ((s0 + s1) + (s2 + s3));
    }

    float acc[4][4] = {};
    const float* Qb = Qp + ((size_t)b * LQ + qb) * H;
    const float* Kb = Kp + ((size_t)b * LK + kb) * H;

    for (int h0 = 0; h0 < H; h0 += 32) {
#pragma unroll
        for (int it = 0; it < 2; ++it) {
            int f = tid + it * 256;
            int r = f >> 3;
            int c = (f & 7) * 4;
            float4 qv = *(const float4*)(Qb + (size_t)r * H + h0 + c);
            Qs[c + 0][r] = qv.x; Qs[c + 1][r] = qv.y;
            Qs[c + 2][r] = qv.z; Qs[c + 3][r] = qv.w;
            float4 kv = *(const float4*)(Kb + (size_t)r * H + h0 + c);
            Ks[c + 0][r] = kv.x; Ks[c + 1][r] = kv.y;
            Ks[c + 2][r] = kv.z; Ks[c + 3][r] = kv.w;
        }
        __syncthreads();
#pragma unroll 4
        for (int h = 0; h < 32; ++h) {
            const float4 q4 = *(const float4*)&Qs[h][tx * 4];
            const float4 k4 = *(const float4*)&Ks[h][ty * 4];
            const float w = Wv2[h0 + h];
            const float qa[4] = {q4.x, q4.y, q4.z, q4.w};
            const float ka[4] = {k4.x, k4.y, k4.z, k4.w};
#pragma unroll
            for (int i = 0; i < 4; ++i)
#pragma unroll
                for (int j = 0; j < 4; ++j) {
                    float x = qa[i] + ka[j];
                    x = fminf(fmaxf(x, -100.f), 100.f);   // keep exp2 finite
                    float t  = __builtin_amdgcn_exp2f(x);
                    float rr = __builtin_amdgcn_rcpf(t + 1.0f);
                    acc[i][j] = fmaf(w, rr, acc[i][j]);
                }
        }
        __syncthreads();
    }
#pragma unroll
    for (int i = 0; i < 4; ++i) {
        int q = qb + tx * 4 + i;
#pragma unroll
        for (int j = 0; j < 4; ++j) {
            int k = kb + ty * 4 + j;
            Sc[((size_t)b * LQ + q) * LK + k] = SW - acc[i][j];
        }
    }
}

// ---------------------------------------------------------------------------
// Kernel C: row softmax in-place on Sc (log2 domain -> plain exp2).
// One block (256 thr) per row of 512; 2 elements/thread.
// ---------------------------------------------------------------------------
__global__ __launch_bounds__(256) void softmax_kernel(float* __restrict__ Sc)
{
    const int row = blockIdx.x;
    float* s = Sc + (size_t)row * LK;
    const int tid = threadIdx.x;
    float2 v = *(float2*)(s + tid * 2);

    float m = fmaxf(v.x, v.y);
#pragma unroll
    for (int off = 32; off >= 1; off >>= 1)
        m = fmaxf(m, __shfl_xor(m, off, 64));
    __shared__ float redm[4];
    const int wid = tid >> 6, lane = tid & 63;
    if (lane == 0) redm[wid] = m;
    __syncthreads();
    m = fmaxf(fmaxf(redm[0], redm[1]), fmaxf(redm[2], redm[3]));

    float e0 = __builtin_amdgcn_exp2f(v.x - m);
    float e1 = __builtin_amdgcn_exp2f(v.y - m);
    float sum = e0 + e1;
#pragma unroll
    for (int off = 32; off >= 1; off >>= 1)
        sum += __shfl_xor(sum, off, 64);
    __shared__ float reds[4];
    if (lane == 0) reds[wid] = sum;
    __syncthreads();
    sum = (reds[0] + reds[1]) + (reds[2] + reds[3]);

    float rs = 1.0f / sum;
    float2 o; o.x = e0 * rs; o.y = e1 * rs;
    *(float2*)(s + tid * 2) = o;
}

// ---------------------------------------------------------------------------
// Kernel D: out = attn @ value.  Per batch [512x512]x[512x512] fp32 NN GEMM.
// Tiles 64x64, BK=32, 256 thr, 4x4/thr. Grid (8,8,B).
// ---------------------------------------------------------------------------
__global__ __launch_bounds__(256) void av_kernel(
    const float* __restrict__ At,   // [B*LQ, LK] attention weights
    const float* __restrict__ V,    // [B, LK, DV]
    float* __restrict__ O)          // [B*LQ, DV]
{
    __shared__ float As[32][64];
    __shared__ float Vs[32][64];
    const int b  = blockIdx.z;
    const int qb = blockIdx.x * 64, nb = blockIdx.y * 64;
    const int tid = threadIdx.x;
    const int tx = tid & 15, ty = tid >> 4;
    float acc[4][4] = {};
    const float* Ab = At + ((size_t)b * LQ + qb) * LK;
    const float* Vb = V + (size_t)b * LK * DV;

    for (int k0 = 0; k0 < LK; k0 += 32) {
#pragma unroll
        for (int it = 0; it < 2; ++it) {
            int f = tid + it * 256;
            int r = f >> 3;              // attn row 0..63
            int c = (f & 7) * 4;         // attn col chunk
            float4 av = *(const float4*)(Ab + (size_t)r * LK + k0 + c);
            As[c + 0][r] = av.x; As[c + 1][r] = av.y;
            As[c + 2][r] = av.z; As[c + 3][r] = av.w;
            int kr = f >> 4;             // V row 0..31
            int c2 = (f & 15) * 4;       // V col chunk 0..60
            float4 vv = *(const float4*)(Vb + (size_t)(k0 + kr) * DV + nb + c2);
            *(float4*)&Vs[kr][c2] = vv;
        }
        __syncthreads();
#pragma unroll
        for (int k = 0; k < 32; ++k) {
            const float4 a4 = *(const float4*)&As[k][tx * 4];
            const float4 v4 = *(const float4*)&Vs[k][ty * 4];
            const float a[4] = {a4.x, a4.y, a4.z, a4.w};
            const float vv[4] = {v4.x, v4.y, v4.z, v4.w};
#pragma unroll
            for (int i = 0; i < 4; ++i)
#pragma unroll
                for (int j = 0; j < 4; ++j)
                    acc[i][j] = fmaf(a[i], vv[j], acc[i][j]);
        }
        __syncthreads();
    }
#pragma unroll
    for (int i = 0; i < 4; ++i) {
        int q = qb + tx * 4 + i;
#pragma unroll
        for (int j = 0; j < 4; ++j) {
            int n = nb + ty * 4 + j;
            O[((size_t)b * LQ + q) * DV + n] = acc[i][j];
        }
    }
}

extern "C" void kernel_launch(void* const* d_in, const int* in_sizes, int n_in,
                              void* d_out, int out_size, void* d_ws, size_t ws_size,
                              hipStream_t stream) {
    const float* query = (const float*)d_in[0];
    const float* key   = (const float*)d_in[1];
    const float* value = (const float*)d_in[2];
    const float* wq    = (const float*)d_in[3];
    const float* bq    = (const float*)d_in[4];
    const float* wk    = (const float*)d_in[5];
    const float* bk    = (const float*)d_in[6];
    const float* wv    = (const float*)d_in[7];
    // d_in[8] = bv: constant shift on all scores in a row -> softmax-invariant,
    // dropped entirely.
    float* out = (float*)d_out;

    float* Qp = (float*)d_ws;                      // [2048, 256] scaled q proj
    float* Kp = Qp + (size_t)Bb * LQ * H;          // [2048, 256] scaled k proj
    float* Sc = Kp + (size_t)Bb * LK * H;          // [2048, 512] scores/attn

    const float c2 = 2.0f * LOG2E;

    proj2_kernel<<<dim3((Bb * LQ) / 64, H / 64, 2), 256, 0, stream>>>(
        query, key, wq, wk, bq, bk, Qp, Kp, c2);
    score_kernel<<<dim3(LQ / 64, LK / 64, Bb), 256, 0, stream>>>(Qp, Kp, wv, Sc);
    softmax_kernel<<<Bb * LQ, 256, 0, stream>>>(Sc);
    av_kernel<<<dim3(LQ / 64, DV / 64, Bb), 256, 0, stream>>>(Sc, value, out);
}

// Round 2
// 201.403 us; speedup vs baseline: 1.0542x; 1.0542x over previous
//
#include <hip/hip_runtime.h>

#define LOG2E 1.4426950408889634f

// Problem constants
constexpr int Bb = 4, LQ = 512, LK = 512, QS = 512, H = 256, DV = 512;
constexpr int M = Bb * LQ;   // 2048 rows for both projections

// ---------------------------------------------------------------------------
// Kernel A: fused Q/K projection + exp2 epilogue, TRANSPOSED output.
//   EqT[n][m] = exp2( clamp( scale*(A[m]·W[n] + bias[n]), ±60 ) )
// so the score kernel can evaluate exp2(c*(q+k)) = EqT*EkT with no exp2 in
// its inner loop.  M = 2048, K = 512, N = H = 256.  Tiles 64x64, BK=32,
// 256 thr, 4x4/thr.  blockIdx.z selects Q (0) vs K (1).
// ---------------------------------------------------------------------------
__global__ __launch_bounds__(256) void proj2_kernel(
    const float* __restrict__ Aq, const float* __restrict__ Ak,
    const float* __restrict__ Wq, const float* __restrict__ Wk,
    const float* __restrict__ Bq, const float* __restrict__ Bk,
    float* __restrict__ EqT, float* __restrict__ EkT, float scale)
{
    const int K = QS;
    const float* A    = blockIdx.z ? Ak : Aq;
    const float* W    = blockIdx.z ? Wk : Wq;
    const float* bias = blockIdx.z ? Bk : Bq;
    float*       C    = blockIdx.z ? EkT : EqT;   // [H][M] transposed

    __shared__ float As[32][64];
    __shared__ float Ws[32][64];
    const int bm = blockIdx.x * 64;
    const int bn = blockIdx.y * 64;
    const int tid = threadIdx.x;
    const int tx = tid & 15, ty = tid >> 4;
    float acc[4][4] = {};

    for (int k0 = 0; k0 < K; k0 += 32) {
#pragma unroll
        for (int it = 0; it < 2; ++it) {
            int f = tid + it * 256;      // 0..511
            int r = f >> 3;              // 0..63
            int c = (f & 7) * 4;         // 0..28
            float4 av = *(const float4*)(A + (size_t)(bm + r) * K + k0 + c);
            As[c + 0][r] = av.x; As[c + 1][r] = av.y;
            As[c + 2][r] = av.z; As[c + 3][r] = av.w;
            float4 wv4 = *(const float4*)(W + (size_t)(bn + r) * K + k0 + c);
            Ws[c + 0][r] = wv4.x; Ws[c + 1][r] = wv4.y;
            Ws[c + 2][r] = wv4.z; Ws[c + 3][r] = wv4.w;
        }
        __syncthreads();
#pragma unroll
        for (int k = 0; k < 32; ++k) {
            const float4 a4 = *(const float4*)&As[k][tx * 4];
            const float4 b4 = *(const float4*)&Ws[k][ty * 4];
            const float a[4] = {a4.x, a4.y, a4.z, a4.w};
            const float b[4] = {b4.x, b4.y, b4.z, b4.w};
#pragma unroll
            for (int i = 0; i < 4; ++i)
#pragma unroll
                for (int j = 0; j < 4; ++j)
                    acc[i][j] = fmaf(a[i], b[j], acc[i][j]);
        }
        __syncthreads();
    }
    // Epilogue: exp2 domain, transposed write.  For each of the thread's 4
    // n-columns, the 4 m-values are contiguous -> float4 store.
#pragma unroll
    for (int j = 0; j < 4; ++j) {
        int n = bn + ty * 4 + j;
        float bs = bias[n];
        float4 o;
        float v0 = scale * (acc[0][j] + bs);
        float v1 = scale * (acc[1][j] + bs);
        float v2 = scale * (acc[2][j] + bs);
        float v3 = scale * (acc[3][j] + bs);
        v0 = fminf(fmaxf(v0, -60.f), 60.f);
        v1 = fminf(fmaxf(v1, -60.f), 60.f);
        v2 = fminf(fmaxf(v2, -60.f), 60.f);
        v3 = fminf(fmaxf(v3, -60.f), 60.f);
        o.x = __builtin_amdgcn_exp2f(v0);
        o.y = __builtin_amdgcn_exp2f(v1);
        o.z = __builtin_amdgcn_exp2f(v2);
        o.w = __builtin_amdgcn_exp2f(v3);
        *(float4*)(C + (size_t)n * M + bm + tx * 4) = o;
    }
}

// ---------------------------------------------------------------------------
// Kernel B: scores (log2 domain, bv dropped).
//   s' = SW - sum_h Wv2[h] * rcp(1 + EqT[h][q]*EkT[h][k])
// Tiles 64(q) x 32(k), h-chunk 32, 256 thr, 4x2/thr.  Grid (8,16,B) = 512
// blocks -> 2 blocks/CU, 2 waves/SIMD.  No LDS transposes: EqT/EkT rows are
// staged with float4 loads + float4 LDS writes (conflict-free).
// ---------------------------------------------------------------------------
__global__ __launch_bounds__(256) void score_kernel(
    const float* __restrict__ EqT,   // [H][M] exp2 domain
    const float* __restrict__ EkT,   // [H][M]
    const float* __restrict__ wv,    // [H]
    float* __restrict__ Sc)          // [B*LQ, LK]
{
    __shared__ float Qs[32][64];
    __shared__ float Ks[32][32];
    __shared__ float Wv2[H];
    const int b  = blockIdx.z;
    const int qb = blockIdx.x * 64, kb = blockIdx.y * 32;
    const int tid = threadIdx.x;
    const int tx = tid & 15;          // q group: 4 rows
    const int ty = tid >> 4;          // k group: 2 cols, 0..15

    Wv2[tid] = wv[tid] * (2.0f * LOG2E);   // blockDim == H == 256
    __syncthreads();

    float SW;
    {
        float s0 = 0.f, s1 = 0.f, s2 = 0.f, s3 = 0.f;
        for (int h = 0; h < H; h += 4) {
            s0 += Wv2[h + 0]; s1 += Wv2[h + 1];
            s2 += Wv2[h + 2]; s3 += Wv2[h + 3];
        }
        SW = 0.5f * ((s0 + s1) + (s2 + s3));
    }

    float acc[4][2] = {};
    const int mq = b * LQ + qb;      // column offset into EqT rows
    const int mk = b * LK + kb;

    for (int h0 = 0; h0 < H; h0 += 32) {
        // stage Qs: 32 h-rows x 64 q-cols = 512 float4 -> 2 iters
#pragma unroll
        for (int it = 0; it < 2; ++it) {
            int idx = tid + it * 256;
            int h = idx >> 4;            // 0..31
            int c = (idx & 15) * 4;      // 0..60
            *(float4*)&Qs[h][c] =
                *(const float4*)(EqT + (size_t)(h0 + h) * M + mq + c);
        }
        // stage Ks: 32 h-rows x 32 k-cols = 256 float4 -> 1 iter
        {
            int h = tid >> 3;            // 0..31
            int c = (tid & 7) * 4;       // 0..28
            *(float4*)&Ks[h][c] =
                *(const float4*)(EkT + (size_t)(h0 + h) * M + mk + c);
        }
        __syncthreads();
#pragma unroll 8
        for (int h = 0; h < 32; ++h) {
            const float4 q4 = *(const float4*)&Qs[h][tx * 4];
            const float2 k2 = *(const float2*)&Ks[h][ty * 2];
            const float w = Wv2[h0 + h];
            const float qa[4] = {q4.x, q4.y, q4.z, q4.w};
            const float ka[2] = {k2.x, k2.y};
#pragma unroll
            for (int i = 0; i < 4; ++i)
#pragma unroll
                for (int j = 0; j < 2; ++j) {
                    float t  = fmaf(qa[i], ka[j], 1.0f);   // 1 + eq*ek, >= 1
                    float rr = __builtin_amdgcn_rcpf(t);
                    acc[i][j] = fmaf(w, rr, acc[i][j]);
                }
        }
        __syncthreads();
    }
#pragma unroll
    for (int i = 0; i < 4; ++i) {
        int q = qb + tx * 4 + i;
        float2 o;
        o.x = SW - acc[i][0];
        o.y = SW - acc[i][1];
        *(float2*)(Sc + ((size_t)b * LQ + q) * LK + kb + ty * 2) = o;
    }
}

// ---------------------------------------------------------------------------
// Kernel C: row softmax in-place on Sc (log2 domain -> plain exp2).
// One block (256 thr) per row of 512; 2 elements/thread.
// ---------------------------------------------------------------------------
__global__ __launch_bounds__(256) void softmax_kernel(float* __restrict__ Sc)
{
    const int row = blockIdx.x;
    float* s = Sc + (size_t)row * LK;
    const int tid = threadIdx.x;
    float2 v = *(float2*)(s + tid * 2);

    float m = fmaxf(v.x, v.y);
#pragma unroll
    for (int off = 32; off >= 1; off >>= 1)
        m = fmaxf(m, __shfl_xor(m, off, 64));
    __shared__ float redm[4];
    const int wid = tid >> 6, lane = tid & 63;
    if (lane == 0) redm[wid] = m;
    __syncthreads();
    m = fmaxf(fmaxf(redm[0], redm[1]), fmaxf(redm[2], redm[3]));

    float e0 = __builtin_amdgcn_exp2f(v.x - m);
    float e1 = __builtin_amdgcn_exp2f(v.y - m);
    float sum = e0 + e1;
#pragma unroll
    for (int off = 32; off >= 1; off >>= 1)
        sum += __shfl_xor(sum, off, 64);
    __shared__ float reds[4];
    if (lane == 0) reds[wid] = sum;
    __syncthreads();
    sum = (reds[0] + reds[1]) + (reds[2] + reds[3]);

    float rs = 1.0f / sum;
    float2 o; o.x = e0 * rs; o.y = e1 * rs;
    *(float2*)(s + tid * 2) = o;
}

// ---------------------------------------------------------------------------
// Kernel D: out = attn @ value.  Per batch [512x512]x[512x512] fp32 NN GEMM.
// Tiles 64x64, BK=32, 256 thr, 4x4/thr. Grid (8,8,B).
// ---------------------------------------------------------------------------
__global__ __launch_bounds__(256) void av_kernel(
    const float* __restrict__ At,   // [B*LQ, LK] attention weights
    const float* __restrict__ V,    // [B, LK, DV]
    float* __restrict__ O)          // [B*LQ, DV]
{
    __shared__ float As[32][64];
    __shared__ float Vs[32][64];
    const int b  = blockIdx.z;
    const int qb = blockIdx.x * 64, nb = blockIdx.y * 64;
    const int tid = threadIdx.x;
    const int tx = tid & 15, ty = tid >> 4;
    float acc[4][4] = {};
    const float* Ab = At + ((size_t)b * LQ + qb) * LK;
    const float* Vb = V + (size_t)b * LK * DV;

    for (int k0 = 0; k0 < LK; k0 += 32) {
#pragma unroll
        for (int it = 0; it < 2; ++it) {
            int f = tid + it * 256;
            int r = f >> 3;              // attn row 0..63
            int c = (f & 7) * 4;         // attn col chunk
            float4 av = *(const float4*)(Ab + (size_t)r * LK + k0 + c);
            As[c + 0][r] = av.x; As[c + 1][r] = av.y;
            As[c + 2][r] = av.z; As[c + 3][r] = av.w;
            int kr = f >> 4;             // V row 0..31
            int c2 = (f & 15) * 4;       // V col chunk 0..60
            float4 vv = *(const float4*)(Vb + (size_t)(k0 + kr) * DV + nb + c2);
            *(float4*)&Vs[kr][c2] = vv;
        }
        __syncthreads();
#pragma unroll
        for (int k = 0; k < 32; ++k) {
            const float4 a4 = *(const float4*)&As[k][tx * 4];
            const float4 v4 = *(const float4*)&Vs[k][ty * 4];
            const float a[4] = {a4.x, a4.y, a4.z, a4.w};
            const float vv[4] = {v4.x, v4.y, v4.z, v4.w};
#pragma unroll
            for (int i = 0; i < 4; ++i)
#pragma unroll
                for (int j = 0; j < 4; ++j)
                    acc[i][j] = fmaf(a[i], vv[j], acc[i][j]);
        }
        __syncthreads();
    }
#pragma unroll
    for (int i = 0; i < 4; ++i) {
        int q = qb + tx * 4 + i;
#pragma unroll
        for (int j = 0; j < 4; ++j) {
            int n = nb + ty * 4 + j;
            O[((size_t)b * LQ + q) * DV + n] = acc[i][j];
        }
    }
}

extern "C" void kernel_launch(void* const* d_in, const int* in_sizes, int n_in,
                              void* d_out, int out_size, void* d_ws, size_t ws_size,
                              hipStream_t stream) {
    const float* query = (const float*)d_in[0];
    const float* key   = (const float*)d_in[1];
    const float* value = (const float*)d_in[2];
    const float* wq    = (const float*)d_in[3];
    const float* bq    = (const float*)d_in[4];
    const float* wk    = (const float*)d_in[5];
    const float* bk    = (const float*)d_in[6];
    const float* wv    = (const float*)d_in[7];
    // d_in[8] = bv: row-constant -> softmax-invariant, dropped.
    float* out = (float*)d_out;

    float* EqT = (float*)d_ws;                     // [H][M] exp2-domain q
    float* EkT = EqT + (size_t)H * M;              // [H][M] exp2-domain k
    float* Sc  = EkT + (size_t)H * M;              // [M][LK] scores/attn

    const float c2 = 2.0f * LOG2E;

    proj2_kernel<<<dim3(M / 64, H / 64, 2), 256, 0, stream>>>(
        query, key, wq, wk, bq, bk, EqT, EkT, c2);
    score_kernel<<<dim3(LQ / 64, LK / 32, Bb), 256, 0, stream>>>(EqT, EkT, wv, Sc);
    softmax_kernel<<<Bb * LQ, 256, 0, stream>>>(Sc);
    av_kernel<<<dim3(LQ / 64, DV / 64, Bb), 256, 0, stream>>>(Sc, value, out);
}